// Round 1
// baseline (200.343 us; speedup 1.0000x reference)
//
#include <hip/hip_runtime.h>
#include <cstdint>
#include <cstddef>

// Problem constants: B=2, T=2048, C=1024, H=16, D=64
#define SEQ_T 2048
#define NHEAD 16

typedef __attribute__((ext_vector_type(8))) short short8;
typedef __attribute__((ext_vector_type(4))) float f32x4;

__device__ __forceinline__ unsigned short f2bf(float f) {
  union { float f; unsigned int u; } v; v.f = f;
  return (unsigned short)((v.u + 0x7FFFu + ((v.u >> 16) & 1u)) >> 16);
}

__device__ __forceinline__ void gl_lds16(const void* g, void* l) {
  __builtin_amdgcn_global_load_lds(
      (__attribute__((address_space(1))) void*)(void*)g,
      (__attribute__((address_space(3))) void*)l, 16, 0, 0);
}

// ---------- fp32 -> bf16 convert (vectorized) ----------
__global__ void k_cvt(const float* __restrict__ in, unsigned short* __restrict__ out, int n4) {
  int i = blockIdx.x * 256 + threadIdx.x;
  if (i >= n4) return;
  float4 v = ((const float4*)in)[i];
  unsigned long long pk = (unsigned long long)f2bf(v.x)
                        | ((unsigned long long)f2bf(v.y) << 16)
                        | ((unsigned long long)f2bf(v.z) << 32)
                        | ((unsigned long long)f2bf(v.w) << 48);
  ((unsigned long long*)out)[i] = pk;
}

// ---------- [K,N] fp32 -> [N,K] bf16 transpose-convert ----------
// thread -> (n, k0..k0+7): reads coalesced along n, writes 16B along K
__global__ void k_tr(const float* __restrict__ in, unsigned short* __restrict__ out, int K, int N) {
  int idx = blockIdx.x * 256 + threadIdx.x;   // N*K/8 threads exactly
  int n = idx % N;
  int k0 = (idx / N) * 8;
  short8 v;
#pragma unroll
  for (int j = 0; j < 8; ++j)
    v[j] = (short)f2bf(in[(size_t)(k0 + j) * N + n]);
  *(short8*)&out[(size_t)n * K + k0] = v;
}

// ---------- RoPE cos/sin table [T][32] ----------
__global__ void k_tab(float2* __restrict__ tab) {
  int idx = blockIdx.x * 256 + threadIdx.x;   // T*32
  int t = idx >> 5, i = idx & 31;
  float inv = powf(10000.0f, -(float)(2 * i) / 64.0f);
  float f = (float)t * inv;
  tab[idx] = make_float2(cosf(f), sinf(f));
}

// ---------- GEMM1: qkv = x @ W_attn^T(+b), fused RoPE, scatter to q/k/v [B,H,T,D] ----------
// m97 structure: 128x128 tile, BK=32, 256 thr / 4 waves (2x2), global_load_lds w=16
__global__ void k_gemm_qkv(const unsigned short* __restrict__ A,   // [4096,1024] bf16
                           const unsigned short* __restrict__ Bt,  // [3072,1024] bf16 (W^T)
                           const float* __restrict__ bias,         // [3072]
                           const float2* __restrict__ cs,          // [2048][32]
                           unsigned short* __restrict__ qo,
                           unsigned short* __restrict__ ko,
                           unsigned short* __restrict__ vo) {
  __shared__ unsigned short lA[128 * 32];
  __shared__ unsigned short lB[128 * 32];
  const int K = 1024;
  const int bn = blockIdx.x, bm = blockIdx.y;
  const int tid = threadIdx.x, w = tid >> 6, l = tid & 63;
  const int lr = l & 15, lh = l >> 4;
  const int wm = w >> 1, wn = w & 1;

  f32x4 acc[4][4];
#pragma unroll
  for (int m = 0; m < 4; ++m)
#pragma unroll
    for (int n = 0; n < 4; ++n)
#pragma unroll
      for (int i = 0; i < 4; ++i) acc[m][n][i] = 0.f;

  const unsigned short* ga0 = A + (size_t)(bm * 128 + w * 16 + (l >> 2)) * K + (l & 3) * 8;
  const unsigned short* gb0 = Bt + (size_t)(bn * 128 + w * 16 + (l >> 2)) * K + (l & 3) * 8;
  unsigned short* la0 = &lA[w * 512];
  unsigned short* la1 = &lA[(w + 4) * 512];
  unsigned short* lb0 = &lB[w * 512];
  unsigned short* lb1 = &lB[(w + 4) * 512];

  for (int kt = 0; kt < K; kt += 32) {
    gl_lds16(ga0 + kt, la0);
    gl_lds16(ga0 + (size_t)64 * K + kt, la1);
    gl_lds16(gb0 + kt, lb0);
    gl_lds16(gb0 + (size_t)64 * K + kt, lb1);
    __syncthreads();
    short8 af[4], bf[4];
#pragma unroll
    for (int m = 0; m < 4; ++m) af[m] = *(const short8*)&lA[(wm * 64 + m * 16 + lr) * 32 + lh * 8];
#pragma unroll
    for (int n = 0; n < 4; ++n) bf[n] = *(const short8*)&lB[(wn * 64 + n * 16 + lr) * 32 + lh * 8];
#pragma unroll
    for (int m = 0; m < 4; ++m)
#pragma unroll
      for (int n = 0; n < 4; ++n)
        acc[m][n] = __builtin_amdgcn_mfma_f32_16x16x32_bf16(af[m], bf[n], acc[m][n], 0, 0, 0);
    __syncthreads();
  }

  // epilogue: bias + RoPE + scatter. Wave's 64-col block is head-aligned.
  const int col0 = bn * 128 + wn * 64;
  const int row0 = bm * 128 + wm * 64;
  const int sec = col0 >> 10;          // 0=q 1=k 2=v
  const int hh = (col0 >> 6) & 15;
  float bl[4];
#pragma unroll
  for (int n = 0; n < 4; ++n) bl[n] = bias[col0 + n * 16 + lr];

  if (sec == 2) {
#pragma unroll
    for (int m = 0; m < 4; ++m)
#pragma unroll
      for (int i = 0; i < 4; ++i) {
        int row = row0 + m * 16 + lh * 4 + i;
        int t = row & 2047, b = row >> 11;
        size_t ob = ((size_t)(b * 16 + hh) * 2048 + t) * 64;
#pragma unroll
        for (int n = 0; n < 4; ++n)
          vo[ob + n * 16 + lr] = f2bf(acc[m][n][i] + bl[n]);
      }
  } else {
    unsigned short* dst = (sec == 0) ? qo : ko;
#pragma unroll
    for (int m = 0; m < 4; ++m)
#pragma unroll
      for (int i = 0; i < 4; ++i) {
        int row = row0 + m * 16 + lh * 4 + i;
        int t = row & 2047, b = row >> 11;
        size_t ob = ((size_t)(b * 16 + hh) * 2048 + t) * 64;
#pragma unroll
        for (int n = 0; n < 4; ++n) {
          float v = acc[m][n][i] + bl[n];
          float pv = acc[m][n ^ 2][i] + bl[n ^ 2];  // partner d +/- 32, same lane
          int d = n * 16 + lr;
          float2 c = cs[t * 32 + (d & 31)];
          float rot = (d < 32) ? -pv : pv;
          dst[ob + d] = f2bf(v * c.x + rot * c.y);
        }
      }
  }
}

// ---------- flash attention: grid (qt=32, bh=32), 256 thr, QBLK=64 (16 rows/wave), KVBLK=64 ----------
__global__ void k_attn(const unsigned short* __restrict__ Q,
                       const unsigned short* __restrict__ Kv,
                       const unsigned short* __restrict__ V,
                       unsigned short* __restrict__ O) {
  __shared__ unsigned short kl[64 * 72];       // K tile [kv][d], pad 72
  __shared__ unsigned short vl[64 * 72];       // V^T tile [d][kv], pad 72
  __shared__ unsigned short pl[4 * 16 * 72];   // per-wave P [16][kv]
  const int bh = blockIdx.y;
  const int qt = blockIdx.x;
  const int tid = threadIdx.x, w = tid >> 6, l = tid & 63;
  const int lr = l & 15, lh = l >> 4;
  const size_t base = (size_t)bh * SEQ_T * 64;

  // Q fragments (A-frag: row=lr, k=lh*8.. ; two K-steps of 32 over D=64)
  const int qrow = qt * 64 + w * 16 + lr;
  short8 qf0 = *(const short8*)&Q[base + (size_t)qrow * 64 + lh * 8];
  short8 qf1 = *(const short8*)&Q[base + (size_t)qrow * 64 + lh * 8 + 32];

  float mi[4], li[4];
  f32x4 ao[4];
#pragma unroll
  for (int i = 0; i < 4; ++i) { mi[i] = -1e30f; li[i] = 0.f; }
#pragma unroll
  for (int n = 0; n < 4; ++n)
#pragma unroll
    for (int i = 0; i < 4; ++i) ao[n][i] = 0.f;

  for (int kt = 0; kt <= qt; ++kt) {
    __syncthreads();
    {
      // K tile row-major (fully coalesced 16B)
      int r = tid >> 3, c8 = tid & 7;
      *(short8*)&kl[r * 72 + c8 * 8] =
          *(const short8*)&Kv[base + (size_t)(kt * 64 + r) * 64 + c8 * 8];
      *(short8*)&kl[(r + 32) * 72 + c8 * 8] =
          *(const short8*)&Kv[base + (size_t)(kt * 64 + r + 32) * 64 + c8 * 8];
      // V transposed: lane d=l, wave owns kv blocks w*8 and w*8+32
      int d = l;
      int kv0 = w * 8;
#pragma unroll
      for (int p = 0; p < 2; ++p) {
        short8 t8;
#pragma unroll
        for (int j = 0; j < 8; ++j)
          t8[j] = (short)V[base + (size_t)(kt * 64 + kv0 + p * 32 + j) * 64 + d];
        *(short8*)&vl[d * 72 + kv0 + p * 32] = t8;
      }
    }
    __syncthreads();

    // S = Q K^T  (per wave: 16 rows x 64 kv)
    f32x4 s[4];
#pragma unroll
    for (int n = 0; n < 4; ++n) {
      short8 kf0 = *(const short8*)&kl[(n * 16 + lr) * 72 + lh * 8];
      short8 kf1 = *(const short8*)&kl[(n * 16 + lr) * 72 + lh * 8 + 32];
      f32x4 a;
#pragma unroll
      for (int i = 0; i < 4; ++i) a[i] = 0.f;
      a = __builtin_amdgcn_mfma_f32_16x16x32_bf16(qf0, kf0, a, 0, 0, 0);
      a = __builtin_amdgcn_mfma_f32_16x16x32_bf16(qf1, kf1, a, 0, 0, 0);
      s[n] = a;
    }

    const float scale = 0.125f;   // 1/sqrt(64)
    const int qrb = qt * 64 + w * 16 + lh * 4;  // + i = this lane's C/D rows
    if (kt == qt) {
#pragma unroll
      for (int n = 0; n < 4; ++n)
#pragma unroll
        for (int i = 0; i < 4; ++i) {
          int kvg = kt * 64 + n * 16 + lr;
          s[n][i] = (kvg <= qrb + i) ? s[n][i] * scale : -1e30f;
        }
    } else {
#pragma unroll
      for (int n = 0; n < 4; ++n)
#pragma unroll
        for (int i = 0; i < 4; ++i) s[n][i] *= scale;
    }

    // online softmax: row max / sum via shfl_xor over low-4 lane bits
    float tm[4];
#pragma unroll
    for (int i = 0; i < 4; ++i)
      tm[i] = fmaxf(fmaxf(s[0][i], s[1][i]), fmaxf(s[2][i], s[3][i]));
#pragma unroll
    for (int off = 1; off <= 8; off <<= 1)
#pragma unroll
      for (int i = 0; i < 4; ++i) tm[i] = fmaxf(tm[i], __shfl_xor(tm[i], off, 64));

    float sc[4];
#pragma unroll
    for (int i = 0; i < 4; ++i) {
      float mn = fmaxf(mi[i], tm[i]);
      sc[i] = __expf(mi[i] - mn);
      mi[i] = mn;
    }
    float rs[4] = {0.f, 0.f, 0.f, 0.f};
#pragma unroll
    for (int n = 0; n < 4; ++n)
#pragma unroll
      for (int i = 0; i < 4; ++i) {
        float p = __expf(s[n][i] - mi[i]);
        s[n][i] = p;
        rs[i] += p;
      }
#pragma unroll
    for (int off = 1; off <= 8; off <<= 1)
#pragma unroll
      for (int i = 0; i < 4; ++i) rs[i] += __shfl_xor(rs[i], off, 64);
#pragma unroll
    for (int i = 0; i < 4; ++i) li[i] = li[i] * sc[i] + rs[i];
#pragma unroll
    for (int n = 0; n < 4; ++n)
#pragma unroll
      for (int i = 0; i < 4; ++i) ao[n][i] *= sc[i];

    // P -> LDS (wave-private) for PV A-fragments
    unsigned short* pw = &pl[w * 16 * 72];
#pragma unroll
    for (int n = 0; n < 4; ++n)
#pragma unroll
      for (int i = 0; i < 4; ++i)
        pw[(lh * 4 + i) * 72 + n * 16 + lr] = f2bf(s[n][i]);

    short8 pa0 = *(const short8*)&pw[lr * 72 + lh * 8];
    short8 pa1 = *(const short8*)&pw[lr * 72 + lh * 8 + 32];
#pragma unroll
    for (int n = 0; n < 4; ++n) {
      short8 vb0 = *(const short8*)&vl[(n * 16 + lr) * 72 + lh * 8];
      short8 vb1 = *(const short8*)&vl[(n * 16 + lr) * 72 + lh * 8 + 32];
      ao[n] = __builtin_amdgcn_mfma_f32_16x16x32_bf16(pa0, vb0, ao[n], 0, 0, 0);
      ao[n] = __builtin_amdgcn_mfma_f32_16x16x32_bf16(pa1, vb1, ao[n], 0, 0, 0);
    }
  }

  // write O in [B,T,C] bf16
  const int hh = bh & 15, bb = bh >> 4;
#pragma unroll
  for (int n = 0; n < 4; ++n)
#pragma unroll
    for (int i = 0; i < 4; ++i) {
      int row = qt * 64 + w * 16 + lh * 4 + i;
      float ov = ao[n][i] / li[i];
      O[((size_t)(bb * 2048 + row)) * 1024 + hh * 64 + n * 16 + lr] = f2bf(ov);
    }
}

// ---------- GEMM2: out = attn_out @ W_proj^T + b (fp32 out) ----------
__global__ void k_gemm_proj(const unsigned short* __restrict__ A,   // [4096,1024] bf16
                            const unsigned short* __restrict__ Bt,  // [1024,1024] bf16
                            const float* __restrict__ bias,         // [1024]
                            float* __restrict__ out) {              // [4096,1024] f32
  __shared__ unsigned short lA[128 * 32];
  __shared__ unsigned short lB[128 * 32];
  const int K = 1024;
  const int bn = blockIdx.x, bm = blockIdx.y;
  const int tid = threadIdx.x, w = tid >> 6, l = tid & 63;
  const int lr = l & 15, lh = l >> 4;
  const int wm = w >> 1, wn = w & 1;

  f32x4 acc[4][4];
#pragma unroll
  for (int m = 0; m < 4; ++m)
#pragma unroll
    for (int n = 0; n < 4; ++n)
#pragma unroll
      for (int i = 0; i < 4; ++i) acc[m][n][i] = 0.f;

  const unsigned short* ga0 = A + (size_t)(bm * 128 + w * 16 + (l >> 2)) * K + (l & 3) * 8;
  const unsigned short* gb0 = Bt + (size_t)(bn * 128 + w * 16 + (l >> 2)) * K + (l & 3) * 8;
  unsigned short* la0 = &lA[w * 512];
  unsigned short* la1 = &lA[(w + 4) * 512];
  unsigned short* lb0 = &lB[w * 512];
  unsigned short* lb1 = &lB[(w + 4) * 512];

  for (int kt = 0; kt < K; kt += 32) {
    gl_lds16(ga0 + kt, la0);
    gl_lds16(ga0 + (size_t)64 * K + kt, la1);
    gl_lds16(gb0 + kt, lb0);
    gl_lds16(gb0 + (size_t)64 * K + kt, lb1);
    __syncthreads();
    short8 af[4], bf[4];
#pragma unroll
    for (int m = 0; m < 4; ++m) af[m] = *(const short8*)&lA[(wm * 64 + m * 16 + lr) * 32 + lh * 8];
#pragma unroll
    for (int n = 0; n < 4; ++n) bf[n] = *(const short8*)&lB[(wn * 64 + n * 16 + lr) * 32 + lh * 8];
#pragma unroll
    for (int m = 0; m < 4; ++m)
#pragma unroll
      for (int n = 0; n < 4; ++n)
        acc[m][n] = __builtin_amdgcn_mfma_f32_16x16x32_bf16(af[m], bf[n], acc[m][n], 0, 0, 0);
    __syncthreads();
  }

  const int col0 = bn * 128 + wn * 64;
  const int row0 = bm * 128 + wm * 64;
  float bl[4];
#pragma unroll
  for (int n = 0; n < 4; ++n) bl[n] = bias[col0 + n * 16 + lr];
#pragma unroll
  for (int m = 0; m < 4; ++m)
#pragma unroll
    for (int i = 0; i < 4; ++i) {
      int row = row0 + m * 16 + lh * 4 + i;
#pragma unroll
      for (int n = 0; n < 4; ++n)
        out[(size_t)row * 1024 + col0 + n * 16 + lr] = acc[m][n][i] + bl[n];
    }
}

extern "C" void kernel_launch(void* const* d_in, const int* in_sizes, int n_in,
                              void* d_out, int out_size, void* d_ws, size_t ws_size,
                              hipStream_t stream) {
  const float* x     = (const float*)d_in[0];   // [2,2048,1024]
  const float* Wattn = (const float*)d_in[1];   // [1024,3072]
  const float* battn = (const float*)d_in[2];   // [3072]
  const float* Wproj = (const float*)d_in[3];   // [1024,1024]
  const float* bproj = (const float*)d_in[4];   // [1024]
  float* out = (float*)d_out;                   // [2,2048,1024] f32

  char* ws = (char*)d_ws;
  unsigned short* xb  = (unsigned short*)(ws);                       // 8 MB  x bf16
  unsigned short* wat = (unsigned short*)(ws + (8ull  << 20));       // 6 MB  W_attn^T bf16
  unsigned short* wpt = (unsigned short*)(ws + (14ull << 20));       // 2 MB  W_proj^T bf16
  unsigned short* qa  = (unsigned short*)(ws + (16ull << 20));       // 8 MB  q [B,H,T,D]
  unsigned short* ka  = (unsigned short*)(ws + (24ull << 20));       // 8 MB  k
  unsigned short* va  = (unsigned short*)(ws + (32ull << 20));       // 8 MB  v
  unsigned short* ob  = (unsigned short*)(ws + (40ull << 20));       // 8 MB  attn out [B,T,C]
  float2* cs          = (float2*)(ws + (48ull << 20));               // 512 KB cos/sin

  k_cvt<<<(4096 * 1024 / 4) / 256, 256, 0, stream>>>(x, xb, 4096 * 1024 / 4);
  k_tr<<<(3072 * 1024 / 8) / 256, 256, 0, stream>>>(Wattn, wat, 1024, 3072);
  k_tr<<<(1024 * 1024 / 8) / 256, 256, 0, stream>>>(Wproj, wpt, 1024, 1024);
  k_tab<<<(2048 * 32) / 256, 256, 0, stream>>>(cs);
  k_gemm_qkv<<<dim3(24, 32), 256, 0, stream>>>(xb, wat, battn, cs, qa, ka, va);
  k_attn<<<dim3(32, 32), 256, 0, stream>>>(qa, ka, va, ob);
  k_gemm_proj<<<dim3(8, 32), 256, 0, stream>>>(ob, wpt, bproj, out);
}

// Round 2
// 155.345 us; speedup vs baseline: 1.2897x; 1.2897x over previous
//
#include <hip/hip_runtime.h>
#include <cstdint>
#include <cstddef>

// Problem constants: B=2, T=2048, C=1024, H=16, D=64
#define SEQ_T 2048
#define NHEAD 16

typedef __attribute__((ext_vector_type(8))) short short8;
typedef __attribute__((ext_vector_type(4))) float f32x4;

__device__ __forceinline__ unsigned short f2bf(float f) {
  union { float f; unsigned int u; } v; v.f = f;
  return (unsigned short)((v.u + 0x7FFFu + ((v.u >> 16) & 1u)) >> 16);
}

__device__ __forceinline__ void gl_lds16(const void* g, void* l) {
  __builtin_amdgcn_global_load_lds(
      (__attribute__((address_space(1))) void*)(void*)g,
      (__attribute__((address_space(3))) void*)l, 16, 0, 0);
}

// ---------- fp32 -> bf16 convert (vectorized) ----------
__global__ void k_cvt(const float* __restrict__ in, unsigned short* __restrict__ out, int n4) {
  int i = blockIdx.x * 256 + threadIdx.x;
  if (i >= n4) return;
  float4 v = ((const float4*)in)[i];
  unsigned long long pk = (unsigned long long)f2bf(v.x)
                        | ((unsigned long long)f2bf(v.y) << 16)
                        | ((unsigned long long)f2bf(v.z) << 32)
                        | ((unsigned long long)f2bf(v.w) << 48);
  ((unsigned long long*)out)[i] = pk;
}

// ---------- [K,N] fp32 -> [N,K] bf16 transpose-convert ----------
__global__ void k_tr(const float* __restrict__ in, unsigned short* __restrict__ out, int K, int N) {
  int idx = blockIdx.x * 256 + threadIdx.x;
  int n = idx % N;
  int k0 = (idx / N) * 8;
  short8 v;
#pragma unroll
  for (int j = 0; j < 8; ++j)
    v[j] = (short)f2bf(in[(size_t)(k0 + j) * N + n]);
  *(short8*)&out[(size_t)n * K + k0] = v;
}

// ---------- RoPE cos/sin table [T][32] ----------
__global__ void k_tab(float2* __restrict__ tab) {
  int idx = blockIdx.x * 256 + threadIdx.x;
  int t = idx >> 5, i = idx & 31;
  float inv = powf(10000.0f, -(float)(2 * i) / 64.0f);
  float f = (float)t * inv;
  tab[idx] = make_float2(cosf(f), sinf(f));
}

// ---------- V transpose: [BH][T][D] -> [BH][D][T], swizzled LDS tile ----------
__global__ void k_trv(const unsigned short* __restrict__ v, unsigned short* __restrict__ vt) {
  __shared__ unsigned short tile[64 * 64];
  const int bh = blockIdx.y;
  const int t0 = blockIdx.x * 64;
  const int tid = threadIdx.x;
  const int r = tid >> 3, c8 = tid & 7;   // r 0..31
  const size_t ib = (size_t)bh * SEQ_T * 64;
  {
    int ch0 = c8 ^ (r & 7) ^ ((r >> 3) & 7);
    *(short8*)&tile[r * 64 + ch0 * 8] =
        *(const short8*)&v[ib + (size_t)(t0 + r) * 64 + c8 * 8];
    int r2 = r + 32;
    int ch1 = c8 ^ (r2 & 7) ^ ((r2 >> 3) & 7);
    *(short8*)&tile[r2 * 64 + ch1 * 8] =
        *(const short8*)&v[ib + (size_t)(t0 + r2) * 64 + c8 * 8];
  }
  __syncthreads();
  const int d = tid >> 3, t8 = tid & 7;
  const size_t ob = (size_t)bh * 64 * SEQ_T;
#pragma unroll
  for (int p = 0; p < 2; ++p) {
    int dd = d + p * 32;
    short8 o;
#pragma unroll
    for (int j = 0; j < 8; ++j) {
      int t = t8 * 8 + j;
      int ch = (dd >> 3) ^ (t & 7) ^ ((t >> 3) & 7);
      o[j] = (short)tile[t * 64 + ch * 8 + (dd & 7)];
    }
    *(short8*)&vt[ob + (size_t)dd * SEQ_T + t0 + t8 * 8] = o;
  }
}

// ---------- GEMM1: qkv = x @ W_attn^T(+b), fused RoPE, scatter to q/k/v [B,H,T,D] ----------
__global__ void k_gemm_qkv(const unsigned short* __restrict__ A,
                           const unsigned short* __restrict__ Bt,
                           const float* __restrict__ bias,
                           const float2* __restrict__ cs,
                           unsigned short* __restrict__ qo,
                           unsigned short* __restrict__ ko,
                           unsigned short* __restrict__ vo) {
  __shared__ unsigned short lA[128 * 32];
  __shared__ unsigned short lB[128 * 32];
  const int K = 1024;
  const int bn = blockIdx.x, bm = blockIdx.y;
  const int tid = threadIdx.x, w = tid >> 6, l = tid & 63;
  const int lr = l & 15, lh = l >> 4;
  const int wm = w >> 1, wn = w & 1;

  f32x4 acc[4][4];
#pragma unroll
  for (int m = 0; m < 4; ++m)
#pragma unroll
    for (int n = 0; n < 4; ++n)
#pragma unroll
      for (int i = 0; i < 4; ++i) acc[m][n][i] = 0.f;

  const unsigned short* ga0 = A + (size_t)(bm * 128 + w * 16 + (l >> 2)) * K + (l & 3) * 8;
  const unsigned short* gb0 = Bt + (size_t)(bn * 128 + w * 16 + (l >> 2)) * K + (l & 3) * 8;
  unsigned short* la0 = &lA[w * 512];
  unsigned short* la1 = &lA[(w + 4) * 512];
  unsigned short* lb0 = &lB[w * 512];
  unsigned short* lb1 = &lB[(w + 4) * 512];

  for (int kt = 0; kt < K; kt += 32) {
    gl_lds16(ga0 + kt, la0);
    gl_lds16(ga0 + (size_t)64 * K + kt, la1);
    gl_lds16(gb0 + kt, lb0);
    gl_lds16(gb0 + (size_t)64 * K + kt, lb1);
    __syncthreads();
    short8 af[4], bf[4];
#pragma unroll
    for (int m = 0; m < 4; ++m) af[m] = *(const short8*)&lA[(wm * 64 + m * 16 + lr) * 32 + lh * 8];
#pragma unroll
    for (int n = 0; n < 4; ++n) bf[n] = *(const short8*)&lB[(wn * 64 + n * 16 + lr) * 32 + lh * 8];
#pragma unroll
    for (int m = 0; m < 4; ++m)
#pragma unroll
      for (int n = 0; n < 4; ++n)
        acc[m][n] = __builtin_amdgcn_mfma_f32_16x16x32_bf16(af[m], bf[n], acc[m][n], 0, 0, 0);
    __syncthreads();
  }

  const int col0 = bn * 128 + wn * 64;
  const int row0 = bm * 128 + wm * 64;
  const int sec = col0 >> 10;
  const int hh = (col0 >> 6) & 15;
  float bl[4];
#pragma unroll
  for (int n = 0; n < 4; ++n) bl[n] = bias[col0 + n * 16 + lr];

  if (sec == 2) {
#pragma unroll
    for (int m = 0; m < 4; ++m)
#pragma unroll
      for (int i = 0; i < 4; ++i) {
        int row = row0 + m * 16 + lh * 4 + i;
        int t = row & 2047, b = row >> 11;
        size_t ob = ((size_t)(b * 16 + hh) * 2048 + t) * 64;
#pragma unroll
        for (int n = 0; n < 4; ++n)
          vo[ob + n * 16 + lr] = f2bf(acc[m][n][i] + bl[n]);
      }
  } else {
    unsigned short* dst = (sec == 0) ? qo : ko;
#pragma unroll
    for (int m = 0; m < 4; ++m)
#pragma unroll
      for (int i = 0; i < 4; ++i) {
        int row = row0 + m * 16 + lh * 4 + i;
        int t = row & 2047, b = row >> 11;
        size_t ob = ((size_t)(b * 16 + hh) * 2048 + t) * 64;
#pragma unroll
        for (int n = 0; n < 4; ++n) {
          float v = acc[m][n][i] + bl[n];
          float pv = acc[m][n ^ 2][i] + bl[n ^ 2];
          int d = n * 16 + lr;
          float2 c = cs[t * 32 + (d & 31)];
          float rot = (d < 32) ? -pv : pv;
          dst[ob + d] = f2bf(v * c.x + rot * c.y);
        }
      }
  }
}

// ---------- flash attention: grid (pair=16, bh=32), 256 thr, QBLK=64, KVBLK=128 ----------
// Paired q-tiles (qt, 31-qt): every block does exactly 17 kt-iterations.
// K tile [128][64] and V^T tile [64][128] staged via global_load_lds with
// pre-swizzled global source (16B-chunk XOR by row&7) -> conflict-free b128 reads.
__global__ void k_attn(const unsigned short* __restrict__ Q,
                       const unsigned short* __restrict__ Kg,
                       const unsigned short* __restrict__ VT,
                       unsigned short* __restrict__ O) {
  __shared__ unsigned short kl[128 * 64];    // [kv][d] chunk-swizzled
  __shared__ unsigned short vl[64 * 128];    // [d][kv] chunk-swizzled
  __shared__ unsigned short pl[4 * 16 * 136];
  const int bh = blockIdx.y;
  const int pr = blockIdx.x;
  const int tid = threadIdx.x, w = tid >> 6, l = tid & 63;
  const int lr = l & 15, lh = l >> 4;
  const size_t base = (size_t)bh * SEQ_T * 64;
  unsigned short* pw = &pl[w * 16 * 136];
  const float CE = 0.18033688f;   // 0.125 * log2(e)

  for (int half = 0; half < 2; ++half) {
    const int qt = half ? (31 - pr) : pr;
    const int qrow = qt * 64 + w * 16 + lr;
    const short8 qf0 = *(const short8*)&Q[base + (size_t)qrow * 64 + lh * 8];
    const short8 qf1 = *(const short8*)&Q[base + (size_t)qrow * 64 + lh * 8 + 32];
    const int qri = qt * 64 + w * 16 + lh * 4;   // + i = lane's C/D rows

    float mi[4], li[4];
    f32x4 ao[4];
#pragma unroll
    for (int i = 0; i < 4; ++i) { mi[i] = -3.0e38f; li[i] = 0.f; }
#pragma unroll
    for (int n = 0; n < 4; ++n)
#pragma unroll
      for (int i = 0; i < 4; ++i) ao[n][i] = 0.f;

    const int nkt = (qt >> 1) + 1;
    for (int kt = 0; kt < nkt; ++kt) {
      __syncthreads();
      // stage K tile: 1024 chunks of 16B, linear LDS, swizzled global source
#pragma unroll
      for (int rep = 0; rep < 4; ++rep) {
        int q = rep * 256 + tid;
        int kv = q >> 3, c = (q & 7) ^ (kv & 7);
        gl_lds16(&Kg[base + (size_t)(kt * 128 + kv) * 64 + c * 8],
                 &kl[(rep * 256 + w * 64) * 8]);
      }
      // stage V^T tile
#pragma unroll
      for (int rep = 0; rep < 4; ++rep) {
        int q = rep * 256 + tid;
        int d = q >> 4, c = (q & 15) ^ (d & 7);
        gl_lds16(&VT[base + (size_t)d * SEQ_T + kt * 128 + c * 8],
                 &vl[(rep * 256 + w * 64) * 8]);
      }
      __syncthreads();

      // S = Q K^T : 8 n-frags of 16 kv
      f32x4 s[8];
#pragma unroll
      for (int n = 0; n < 8; ++n) {
        int r = n * 16 + lr;
        const short8 kf0 = *(const short8*)&kl[r * 64 + ((lh ^ (r & 7)) * 8)];
        const short8 kf1 = *(const short8*)&kl[r * 64 + (((lh + 4) ^ (r & 7)) * 8)];
        f32x4 a;
#pragma unroll
        for (int i = 0; i < 4; ++i) a[i] = 0.f;
        a = __builtin_amdgcn_mfma_f32_16x16x32_bf16(qf0, kf0, a, 0, 0, 0);
        a = __builtin_amdgcn_mfma_f32_16x16x32_bf16(qf1, kf1, a, 0, 0, 0);
        s[n] = a;
      }

      if (kt == nkt - 1) {   // diagonal block: causal mask (unscaled scores)
#pragma unroll
        for (int n = 0; n < 8; ++n)
#pragma unroll
          for (int i = 0; i < 4; ++i) {
            int kvg = kt * 128 + n * 16 + lr;
            if (kvg > qri + i) s[n][i] = -3.0e38f;
          }
      }

      // online softmax on unscaled scores: p = exp2((s - m) * CE)
      float tm[4];
#pragma unroll
      for (int i = 0; i < 4; ++i) {
        float a0 = fmaxf(fmaxf(s[0][i], s[1][i]), fmaxf(s[2][i], s[3][i]));
        float a1 = fmaxf(fmaxf(s[4][i], s[5][i]), fmaxf(s[6][i], s[7][i]));
        tm[i] = fmaxf(a0, a1);
      }
#pragma unroll
      for (int off = 1; off <= 8; off <<= 1)
#pragma unroll
        for (int i = 0; i < 4; ++i) tm[i] = fmaxf(tm[i], __shfl_xor(tm[i], off, 64));

      float sc[4];
#pragma unroll
      for (int i = 0; i < 4; ++i) {
        float mn = fmaxf(mi[i], tm[i]);
        sc[i] = exp2f((mi[i] - mn) * CE);
        mi[i] = mn;
      }
      float rs[4] = {0.f, 0.f, 0.f, 0.f};
#pragma unroll
      for (int n = 0; n < 8; ++n)
#pragma unroll
        for (int i = 0; i < 4; ++i) {
          float p = exp2f((s[n][i] - mi[i]) * CE);
          s[n][i] = p;
          rs[i] += p;
        }
#pragma unroll
      for (int off = 1; off <= 8; off <<= 1)
#pragma unroll
        for (int i = 0; i < 4; ++i) rs[i] += __shfl_xor(rs[i], off, 64);
#pragma unroll
      for (int i = 0; i < 4; ++i) li[i] = li[i] * sc[i] + rs[i];
#pragma unroll
      for (int n = 0; n < 4; ++n)
#pragma unroll
        for (int i = 0; i < 4; ++i) ao[n][i] *= sc[i];

      // P -> LDS (wave-private, stride 136 shorts = 17x16B: aligned, low-conflict)
#pragma unroll
      for (int n = 0; n < 8; ++n)
#pragma unroll
        for (int i = 0; i < 4; ++i)
          pw[(lh * 4 + i) * 136 + n * 16 + lr] = f2bf(s[n][i]);

      short8 pa[4];
#pragma unroll
      for (int ks = 0; ks < 4; ++ks)
        pa[ks] = *(const short8*)&pw[lr * 136 + ks * 32 + lh * 8];

      // O += P V : 4 d-frags x 4 k-steps
#pragma unroll
      for (int n = 0; n < 4; ++n) {
        int r = n * 16 + lr;
#pragma unroll
        for (int ks = 0; ks < 4; ++ks) {
          const short8 vb = *(const short8*)&vl[r * 128 + (((ks * 4 + lh) ^ (r & 7)) * 8)];
          ao[n] = __builtin_amdgcn_mfma_f32_16x16x32_bf16(pa[ks], vb, ao[n], 0, 0, 0);
        }
      }
    }

    // write O in [B,T,C] bf16
    const int hh = bh & 15, bb = bh >> 4;
#pragma unroll
    for (int n = 0; n < 4; ++n)
#pragma unroll
      for (int i = 0; i < 4; ++i) {
        int row = qt * 64 + w * 16 + lh * 4 + i;
        float ov = ao[n][i] / li[i];
        O[((size_t)(bb * 2048 + row)) * 1024 + hh * 64 + n * 16 + lr] = f2bf(ov);
      }
  }
}

// ---------- GEMM2: out = attn_out @ W_proj^T + b (fp32 out) ----------
__global__ void k_gemm_proj(const unsigned short* __restrict__ A,
                            const unsigned short* __restrict__ Bt,
                            const float* __restrict__ bias,
                            float* __restrict__ out) {
  __shared__ unsigned short lA[128 * 32];
  __shared__ unsigned short lB[128 * 32];
  const int K = 1024;
  const int bn = blockIdx.x, bm = blockIdx.y;
  const int tid = threadIdx.x, w = tid >> 6, l = tid & 63;
  const int lr = l & 15, lh = l >> 4;
  const int wm = w >> 1, wn = w & 1;

  f32x4 acc[4][4];
#pragma unroll
  for (int m = 0; m < 4; ++m)
#pragma unroll
    for (int n = 0; n < 4; ++n)
#pragma unroll
      for (int i = 0; i < 4; ++i) acc[m][n][i] = 0.f;

  const unsigned short* ga0 = A + (size_t)(bm * 128 + w * 16 + (l >> 2)) * K + (l & 3) * 8;
  const unsigned short* gb0 = Bt + (size_t)(bn * 128 + w * 16 + (l >> 2)) * K + (l & 3) * 8;
  unsigned short* la0 = &lA[w * 512];
  unsigned short* la1 = &lA[(w + 4) * 512];
  unsigned short* lb0 = &lB[w * 512];
  unsigned short* lb1 = &lB[(w + 4) * 512];

  for (int kt = 0; kt < K; kt += 32) {
    gl_lds16(ga0 + kt, la0);
    gl_lds16(ga0 + (size_t)64 * K + kt, la1);
    gl_lds16(gb0 + kt, lb0);
    gl_lds16(gb0 + (size_t)64 * K + kt, lb1);
    __syncthreads();
    short8 af[4], bf[4];
#pragma unroll
    for (int m = 0; m < 4; ++m) af[m] = *(const short8*)&lA[(wm * 64 + m * 16 + lr) * 32 + lh * 8];
#pragma unroll
    for (int n = 0; n < 4; ++n) bf[n] = *(const short8*)&lB[(wn * 64 + n * 16 + lr) * 32 + lh * 8];
#pragma unroll
    for (int m = 0; m < 4; ++m)
#pragma unroll
      for (int n = 0; n < 4; ++n)
        acc[m][n] = __builtin_amdgcn_mfma_f32_16x16x32_bf16(af[m], bf[n], acc[m][n], 0, 0, 0);
    __syncthreads();
  }

  const int col0 = bn * 128 + wn * 64;
  const int row0 = bm * 128 + wm * 64;
  float bl[4];
#pragma unroll
  for (int n = 0; n < 4; ++n) bl[n] = bias[col0 + n * 16 + lr];
#pragma unroll
  for (int m = 0; m < 4; ++m)
#pragma unroll
    for (int i = 0; i < 4; ++i) {
      int row = row0 + m * 16 + lh * 4 + i;
#pragma unroll
      for (int n = 0; n < 4; ++n)
        out[(size_t)row * 1024 + col0 + n * 16 + lr] = acc[m][n][i] + bl[n];
    }
}

extern "C" void kernel_launch(void* const* d_in, const int* in_sizes, int n_in,
                              void* d_out, int out_size, void* d_ws, size_t ws_size,
                              hipStream_t stream) {
  const float* x     = (const float*)d_in[0];
  const float* Wattn = (const float*)d_in[1];
  const float* battn = (const float*)d_in[2];
  const float* Wproj = (const float*)d_in[3];
  const float* bproj = (const float*)d_in[4];
  float* out = (float*)d_out;

  char* ws = (char*)d_ws;
  unsigned short* xb  = (unsigned short*)(ws);                  // 8 MB  x bf16 (reused as vt)
  unsigned short* wat = (unsigned short*)(ws + (8ull  << 20));  // 6 MB
  unsigned short* wpt = (unsigned short*)(ws + (14ull << 20));  // 2 MB
  unsigned short* qa  = (unsigned short*)(ws + (16ull << 20));  // 8 MB
  unsigned short* ka  = (unsigned short*)(ws + (24ull << 20));  // 8 MB
  unsigned short* va  = (unsigned short*)(ws + (32ull << 20));  // 8 MB
  unsigned short* ob  = (unsigned short*)(ws + (40ull << 20));  // 8 MB
  float2* cs          = (float2*)(ws + (48ull << 20));          // 512 KB
  unsigned short* vt  = xb;   // x bf16 dead after GEMM1; reuse for V^T

  k_cvt<<<(4096 * 1024 / 4) / 256, 256, 0, stream>>>(x, xb, 4096 * 1024 / 4);
  k_tr<<<(3072 * 1024 / 8) / 256, 256, 0, stream>>>(Wattn, wat, 1024, 3072);
  k_tr<<<(1024 * 1024 / 8) / 256, 256, 0, stream>>>(Wproj, wpt, 1024, 1024);
  k_tab<<<(2048 * 32) / 256, 256, 0, stream>>>(cs);
  k_gemm_qkv<<<dim3(24, 32), 256, 0, stream>>>(xb, wat, battn, cs, qa, ka, va);
  k_trv<<<dim3(32, 32), 256, 0, stream>>>(va, vt);
  k_attn<<<dim3(16, 32), 256, 0, stream>>>(qa, ka, vt, ob);
  k_gemm_proj<<<dim3(8, 32), 256, 0, stream>>>(ob, wpt, bproj, out);
}

// Round 3
// 153.882 us; speedup vs baseline: 1.3019x; 1.0095x over previous
//
#include <hip/hip_runtime.h>
#include <cstdint>
#include <cstddef>

// Problem constants: B=2, T=2048, C=1024, H=16, D=64
#define SEQ_T 2048
#define NHEAD 16

typedef __attribute__((ext_vector_type(8))) short short8;
typedef __attribute__((ext_vector_type(4))) float f32x4;

__device__ __forceinline__ unsigned short f2bf(float f) {
  union { float f; unsigned int u; } v; v.f = f;
  return (unsigned short)((v.u + 0x7FFFu + ((v.u >> 16) & 1u)) >> 16);
}

__device__ __forceinline__ void gl_lds16(const void* g, void* l) {
  __builtin_amdgcn_global_load_lds(
      (__attribute__((address_space(1))) void*)(void*)g,
      (__attribute__((address_space(3))) void*)l, 16, 0, 0);
}

// ---------- fp32 -> bf16 convert (vectorized) ----------
__global__ void k_cvt(const float* __restrict__ in, unsigned short* __restrict__ out, int n4) {
  int i = blockIdx.x * 256 + threadIdx.x;
  if (i >= n4) return;
  float4 v = ((const float4*)in)[i];
  unsigned long long pk = (unsigned long long)f2bf(v.x)
                        | ((unsigned long long)f2bf(v.y) << 16)
                        | ((unsigned long long)f2bf(v.z) << 32)
                        | ((unsigned long long)f2bf(v.w) << 48);
  ((unsigned long long*)out)[i] = pk;
}

// ---------- [K,N] fp32 -> [N,K] bf16 transpose-convert ----------
__global__ void k_tr(const float* __restrict__ in, unsigned short* __restrict__ out, int K, int N) {
  int idx = blockIdx.x * 256 + threadIdx.x;
  int n = idx % N;
  int k0 = (idx / N) * 8;
  short8 v;
#pragma unroll
  for (int j = 0; j < 8; ++j)
    v[j] = (short)f2bf(in[(size_t)(k0 + j) * N + n]);
  *(short8*)&out[(size_t)n * K + k0] = v;
}

// ---------- RoPE cos/sin table [T][32] ----------
__global__ void k_tab(float2* __restrict__ tab) {
  int idx = blockIdx.x * 256 + threadIdx.x;
  int t = idx >> 5, i = idx & 31;
  float inv = powf(10000.0f, -(float)(2 * i) / 64.0f);
  float f = (float)t * inv;
  tab[idx] = make_float2(cosf(f), sinf(f));
}

// ---------- V transpose: [BH][T][D] -> [BH][D][T], swizzled LDS tile ----------
__global__ void k_trv(const unsigned short* __restrict__ v, unsigned short* __restrict__ vt) {
  __shared__ unsigned short tile[64 * 64];
  const int bh = blockIdx.y;
  const int t0 = blockIdx.x * 64;
  const int tid = threadIdx.x;
  const int r = tid >> 3, c8 = tid & 7;   // r 0..31
  const size_t ib = (size_t)bh * SEQ_T * 64;
  {
    int ch0 = c8 ^ (r & 7) ^ ((r >> 3) & 7);
    *(short8*)&tile[r * 64 + ch0 * 8] =
        *(const short8*)&v[ib + (size_t)(t0 + r) * 64 + c8 * 8];
    int r2 = r + 32;
    int ch1 = c8 ^ (r2 & 7) ^ ((r2 >> 3) & 7);
    *(short8*)&tile[r2 * 64 + ch1 * 8] =
        *(const short8*)&v[ib + (size_t)(t0 + r2) * 64 + c8 * 8];
  }
  __syncthreads();
  const int d = tid >> 3, t8 = tid & 7;
  const size_t ob = (size_t)bh * 64 * SEQ_T;
#pragma unroll
  for (int p = 0; p < 2; ++p) {
    int dd = d + p * 32;
    short8 o;
#pragma unroll
    for (int j = 0; j < 8; ++j) {
      int t = t8 * 8 + j;
      int ch = (dd >> 3) ^ (t & 7) ^ ((t >> 3) & 7);
      o[j] = (short)tile[t * 64 + ch * 8 + (dd & 7)];
    }
    *(short8*)&vt[ob + (size_t)dd * SEQ_T + t0 + t8 * 8] = o;
  }
}

// ---------- GEMM1: qkv = x @ W_attn^T(+b), fused RoPE, scatter to q/k/v [B,H,T,D] ----------
__global__ void k_gemm_qkv(const unsigned short* __restrict__ A,
                           const unsigned short* __restrict__ Bt,
                           const float* __restrict__ bias,
                           const float2* __restrict__ cs,
                           unsigned short* __restrict__ qo,
                           unsigned short* __restrict__ ko,
                           unsigned short* __restrict__ vo) {
  __shared__ unsigned short lA[128 * 32];
  __shared__ unsigned short lB[128 * 32];
  const int K = 1024;
  const int bn = blockIdx.x, bm = blockIdx.y;
  const int tid = threadIdx.x, w = tid >> 6, l = tid & 63;
  const int lr = l & 15, lh = l >> 4;
  const int wm = w >> 1, wn = w & 1;

  f32x4 acc[4][4];
#pragma unroll
  for (int m = 0; m < 4; ++m)
#pragma unroll
    for (int n = 0; n < 4; ++n)
#pragma unroll
      for (int i = 0; i < 4; ++i) acc[m][n][i] = 0.f;

  const unsigned short* ga0 = A + (size_t)(bm * 128 + w * 16 + (l >> 2)) * K + (l & 3) * 8;
  const unsigned short* gb0 = Bt + (size_t)(bn * 128 + w * 16 + (l >> 2)) * K + (l & 3) * 8;
  unsigned short* la0 = &lA[w * 512];
  unsigned short* la1 = &lA[(w + 4) * 512];
  unsigned short* lb0 = &lB[w * 512];
  unsigned short* lb1 = &lB[(w + 4) * 512];

  for (int kt = 0; kt < K; kt += 32) {
    gl_lds16(ga0 + kt, la0);
    gl_lds16(ga0 + (size_t)64 * K + kt, la1);
    gl_lds16(gb0 + kt, lb0);
    gl_lds16(gb0 + (size_t)64 * K + kt, lb1);
    __syncthreads();
    short8 af[4], bf[4];
#pragma unroll
    for (int m = 0; m < 4; ++m) af[m] = *(const short8*)&lA[(wm * 64 + m * 16 + lr) * 32 + lh * 8];
#pragma unroll
    for (int n = 0; n < 4; ++n) bf[n] = *(const short8*)&lB[(wn * 64 + n * 16 + lr) * 32 + lh * 8];
#pragma unroll
    for (int m = 0; m < 4; ++m)
#pragma unroll
      for (int n = 0; n < 4; ++n)
        acc[m][n] = __builtin_amdgcn_mfma_f32_16x16x32_bf16(af[m], bf[n], acc[m][n], 0, 0, 0);
    __syncthreads();
  }

  const int col0 = bn * 128 + wn * 64;
  const int row0 = bm * 128 + wm * 64;
  const int sec = col0 >> 10;
  const int hh = (col0 >> 6) & 15;
  float bl[4];
#pragma unroll
  for (int n = 0; n < 4; ++n) bl[n] = bias[col0 + n * 16 + lr];

  if (sec == 2) {
#pragma unroll
    for (int m = 0; m < 4; ++m)
#pragma unroll
      for (int i = 0; i < 4; ++i) {
        int row = row0 + m * 16 + lh * 4 + i;
        int t = row & 2047, b = row >> 11;
        size_t ob = ((size_t)(b * 16 + hh) * 2048 + t) * 64;
#pragma unroll
        for (int n = 0; n < 4; ++n)
          vo[ob + n * 16 + lr] = f2bf(acc[m][n][i] + bl[n]);
      }
  } else {
    unsigned short* dst = (sec == 0) ? qo : ko;
#pragma unroll
    for (int m = 0; m < 4; ++m)
#pragma unroll
      for (int i = 0; i < 4; ++i) {
        int row = row0 + m * 16 + lh * 4 + i;
        int t = row & 2047, b = row >> 11;
        size_t ob = ((size_t)(b * 16 + hh) * 2048 + t) * 64;
#pragma unroll
        for (int n = 0; n < 4; ++n) {
          float v = acc[m][n][i] + bl[n];
          float pv = acc[m][n ^ 2][i] + bl[n ^ 2];
          int d = n * 16 + lr;
          float2 c = cs[t * 32 + (d & 31)];
          float rot = (d < 32) ? -pv : pv;
          dst[ob + d] = f2bf(v * c.x + rot * c.y);
        }
      }
  }
}

// ---------- flash attention: 1D grid 512 (XCD-chunked), 256 thr, QBLK=64, KVBLK=128 ----------
// XCD swizzle: id%8 = XCD; each XCD owns 4 heads x 16 q-pair blocks -> K/V L2-resident (2MB/XCD).
// Paired q-tiles (qt, 31-qt): every block does exactly 17 kt-iterations.
__global__ void k_attn(const unsigned short* __restrict__ Q,
                       const unsigned short* __restrict__ Kg,
                       const unsigned short* __restrict__ VT,
                       unsigned short* __restrict__ O) {
  __shared__ unsigned short kl[128 * 64];    // [kv][d] chunk-swizzled
  __shared__ unsigned short vl[64 * 128];    // [d][kv] chunk-swizzled
  __shared__ unsigned short pl[4 * 16 * 136];
  const int id = blockIdx.x;
  const int xcd = id & 7, slot = id >> 3;
  const int bh = xcd * 4 + (slot >> 4);      // 4 heads per XCD
  const int pr = slot & 15;
  const int tid = threadIdx.x, w = tid >> 6, l = tid & 63;
  const int lr = l & 15, lh = l >> 4;
  const size_t base = (size_t)bh * SEQ_T * 64;
  unsigned short* pw = &pl[w * 16 * 136];
  const float CE = 0.18033688f;   // 0.125 * log2(e)
  const float DTHR = 44.3614f;    // 8 / CE  (defer-rescale threshold, T13)

  for (int half = 0; half < 2; ++half) {
    const int qt = half ? (31 - pr) : pr;
    const int qrow = qt * 64 + w * 16 + lr;
    const short8 qf0 = *(const short8*)&Q[base + (size_t)qrow * 64 + lh * 8];
    const short8 qf1 = *(const short8*)&Q[base + (size_t)qrow * 64 + lh * 8 + 32];
    const int qri = qt * 64 + w * 16 + lh * 4;   // + i = lane's C/D rows

    float mi[4], li[4];
    f32x4 ao[4];
#pragma unroll
    for (int i = 0; i < 4; ++i) { mi[i] = -3.0e38f; li[i] = 0.f; }
#pragma unroll
    for (int n = 0; n < 4; ++n)
#pragma unroll
      for (int i = 0; i < 4; ++i) ao[n][i] = 0.f;

    const int nkt = (qt >> 1) + 1;
    for (int kt = 0; kt < nkt; ++kt) {
      __syncthreads();
      // stage K tile: 1024 chunks of 16B, linear LDS, swizzled global source
#pragma unroll
      for (int rep = 0; rep < 4; ++rep) {
        int q = rep * 256 + tid;
        int kv = q >> 3, c = (q & 7) ^ (kv & 7);
        gl_lds16(&Kg[base + (size_t)(kt * 128 + kv) * 64 + c * 8],
                 &kl[(rep * 256 + w * 64) * 8]);
      }
      // stage V^T tile
#pragma unroll
      for (int rep = 0; rep < 4; ++rep) {
        int q = rep * 256 + tid;
        int d = q >> 4, c = (q & 15) ^ (d & 7);
        gl_lds16(&VT[base + (size_t)d * SEQ_T + kt * 128 + c * 8],
                 &vl[(rep * 256 + w * 64) * 8]);
      }
      __syncthreads();

      // S = Q K^T : 8 n-frags of 16 kv
      f32x4 s[8];
      __builtin_amdgcn_s_setprio(1);
#pragma unroll
      for (int n = 0; n < 8; ++n) {
        int r = n * 16 + lr;
        const short8 kf0 = *(const short8*)&kl[r * 64 + ((lh ^ (r & 7)) * 8)];
        const short8 kf1 = *(const short8*)&kl[r * 64 + (((lh + 4) ^ (r & 7)) * 8)];
        f32x4 a;
#pragma unroll
        for (int i = 0; i < 4; ++i) a[i] = 0.f;
        a = __builtin_amdgcn_mfma_f32_16x16x32_bf16(qf0, kf0, a, 0, 0, 0);
        a = __builtin_amdgcn_mfma_f32_16x16x32_bf16(qf1, kf1, a, 0, 0, 0);
        s[n] = a;
      }
      __builtin_amdgcn_s_setprio(0);

      if (kt == nkt - 1) {   // diagonal block: causal mask (unscaled scores)
#pragma unroll
        for (int n = 0; n < 8; ++n)
#pragma unroll
          for (int i = 0; i < 4; ++i) {
            int kvg = kt * 128 + n * 16 + lr;
            if (kvg > qri + i) s[n][i] = -3.0e38f;
          }
      }

      // online softmax on unscaled scores: p = exp2((s - m) * CE)
      float tm[4];
#pragma unroll
      for (int i = 0; i < 4; ++i) {
        float a0 = fmaxf(fmaxf(s[0][i], s[1][i]), fmaxf(s[2][i], s[3][i]));
        float a1 = fmaxf(fmaxf(s[4][i], s[5][i]), fmaxf(s[6][i], s[7][i]));
        tm[i] = fmaxf(a0, a1);
      }
#pragma unroll
      for (int off = 1; off <= 8; off <<= 1)
#pragma unroll
        for (int i = 0; i < 4; ++i) tm[i] = fmaxf(tm[i], __shfl_xor(tm[i], off, 64));

      // T13 defer-rescale: skip O/l rescale while tile max stays within threshold
      bool within = true;
#pragma unroll
      for (int i = 0; i < 4; ++i) within = within && (tm[i] <= mi[i] + DTHR);
      if (!__all(within)) {
        float sc[4];
#pragma unroll
        for (int i = 0; i < 4; ++i) {
          float mn = fmaxf(mi[i], tm[i]);
          sc[i] = exp2f((mi[i] - mn) * CE);
          mi[i] = mn;
        }
#pragma unroll
        for (int i = 0; i < 4; ++i) li[i] *= sc[i];
#pragma unroll
        for (int n = 0; n < 4; ++n)
#pragma unroll
          for (int i = 0; i < 4; ++i) ao[n][i] *= sc[i];
      }

      float rs[4] = {0.f, 0.f, 0.f, 0.f};
#pragma unroll
      for (int n = 0; n < 8; ++n)
#pragma unroll
        for (int i = 0; i < 4; ++i) {
          float p = exp2f((s[n][i] - mi[i]) * CE);
          s[n][i] = p;
          rs[i] += p;
        }
#pragma unroll
      for (int off = 1; off <= 8; off <<= 1)
#pragma unroll
        for (int i = 0; i < 4; ++i) rs[i] += __shfl_xor(rs[i], off, 64);
#pragma unroll
      for (int i = 0; i < 4; ++i) li[i] += rs[i];

      // P -> LDS (wave-private, stride 136 shorts)
#pragma unroll
      for (int n = 0; n < 8; ++n)
#pragma unroll
        for (int i = 0; i < 4; ++i)
          pw[(lh * 4 + i) * 136 + n * 16 + lr] = f2bf(s[n][i]);

      short8 pa[4];
#pragma unroll
      for (int ks = 0; ks < 4; ++ks)
        pa[ks] = *(const short8*)&pw[lr * 136 + ks * 32 + lh * 8];

      // O += P V : 4 d-frags x 4 k-steps
      __builtin_amdgcn_s_setprio(1);
#pragma unroll
      for (int n = 0; n < 4; ++n) {
        int r = n * 16 + lr;
#pragma unroll
        for (int ks = 0; ks < 4; ++ks) {
          const short8 vb = *(const short8*)&vl[r * 128 + (((ks * 4 + lh) ^ (r & 7)) * 8)];
          ao[n] = __builtin_amdgcn_mfma_f32_16x16x32_bf16(pa[ks], vb, ao[n], 0, 0, 0);
        }
      }
      __builtin_amdgcn_s_setprio(0);
    }

    // write O in [B,T,C] bf16
    const int hh = bh & 15, bb = bh >> 4;
#pragma unroll
    for (int n = 0; n < 4; ++n)
#pragma unroll
      for (int i = 0; i < 4; ++i) {
        int row = qt * 64 + w * 16 + lh * 4 + i;
        float ov = ao[n][i] / li[i];
        O[((size_t)(bb * 2048 + row)) * 1024 + hh * 64 + n * 16 + lr] = f2bf(ov);
      }
  }
}

// ---------- GEMM2: out = attn_out @ W_proj^T + b (fp32 out) ----------
__global__ void k_gemm_proj(const unsigned short* __restrict__ A,
                            const unsigned short* __restrict__ Bt,
                            const float* __restrict__ bias,
                            float* __restrict__ out) {
  __shared__ unsigned short lA[128 * 32];
  __shared__ unsigned short lB[128 * 32];
  const int K = 1024;
  const int bn = blockIdx.x, bm = blockIdx.y;
  const int tid = threadIdx.x, w = tid >> 6, l = tid & 63;
  const int lr = l & 15, lh = l >> 4;
  const int wm = w >> 1, wn = w & 1;

  f32x4 acc[4][4];
#pragma unroll
  for (int m = 0; m < 4; ++m)
#pragma unroll
    for (int n = 0; n < 4; ++n)
#pragma unroll
      for (int i = 0; i < 4; ++i) acc[m][n][i] = 0.f;

  const unsigned short* ga0 = A + (size_t)(bm * 128 + w * 16 + (l >> 2)) * K + (l & 3) * 8;
  const unsigned short* gb0 = Bt + (size_t)(bn * 128 + w * 16 + (l >> 2)) * K + (l & 3) * 8;
  unsigned short* la0 = &lA[w * 512];
  unsigned short* la1 = &lA[(w + 4) * 512];
  unsigned short* lb0 = &lB[w * 512];
  unsigned short* lb1 = &lB[(w + 4) * 512];

  for (int kt = 0; kt < K; kt += 32) {
    gl_lds16(ga0 + kt, la0);
    gl_lds16(ga0 + (size_t)64 * K + kt, la1);
    gl_lds16(gb0 + kt, lb0);
    gl_lds16(gb0 + (size_t)64 * K + kt, lb1);
    __syncthreads();
    short8 af[4], bf[4];
#pragma unroll
    for (int m = 0; m < 4; ++m) af[m] = *(const short8*)&lA[(wm * 64 + m * 16 + lr) * 32 + lh * 8];
#pragma unroll
    for (int n = 0; n < 4; ++n) bf[n] = *(const short8*)&lB[(wn * 64 + n * 16 + lr) * 32 + lh * 8];
#pragma unroll
    for (int m = 0; m < 4; ++m)
#pragma unroll
      for (int n = 0; n < 4; ++n)
        acc[m][n] = __builtin_amdgcn_mfma_f32_16x16x32_bf16(af[m], bf[n], acc[m][n], 0, 0, 0);
    __syncthreads();
  }

  const int col0 = bn * 128 + wn * 64;
  const int row0 = bm * 128 + wm * 64;
  float bl[4];
#pragma unroll
  for (int n = 0; n < 4; ++n) bl[n] = bias[col0 + n * 16 + lr];
#pragma unroll
  for (int m = 0; m < 4; ++m)
#pragma unroll
    for (int i = 0; i < 4; ++i) {
      int row = row0 + m * 16 + lh * 4 + i;
#pragma unroll
      for (int n = 0; n < 4; ++n)
        out[(size_t)row * 1024 + col0 + n * 16 + lr] = acc[m][n][i] + bl[n];
    }
}

extern "C" void kernel_launch(void* const* d_in, const int* in_sizes, int n_in,
                              void* d_out, int out_size, void* d_ws, size_t ws_size,
                              hipStream_t stream) {
  const float* x     = (const float*)d_in[0];
  const float* Wattn = (const float*)d_in[1];
  const float* battn = (const float*)d_in[2];
  const float* Wproj = (const float*)d_in[3];
  const float* bproj = (const float*)d_in[4];
  float* out = (float*)d_out;

  char* ws = (char*)d_ws;
  unsigned short* xb  = (unsigned short*)(ws);                  // 8 MB  x bf16 (reused as vt)
  unsigned short* wat = (unsigned short*)(ws + (8ull  << 20));  // 6 MB
  unsigned short* wpt = (unsigned short*)(ws + (14ull << 20));  // 2 MB
  unsigned short* qa  = (unsigned short*)(ws + (16ull << 20));  // 8 MB
  unsigned short* ka  = (unsigned short*)(ws + (24ull << 20));  // 8 MB
  unsigned short* va  = (unsigned short*)(ws + (32ull << 20));  // 8 MB
  unsigned short* ob  = (unsigned short*)(ws + (40ull << 20));  // 8 MB
  float2* cs          = (float2*)(ws + (48ull << 20));          // 512 KB
  unsigned short* vt  = xb;   // x bf16 dead after GEMM1; reuse for V^T

  k_cvt<<<(4096 * 1024 / 4) / 256, 256, 0, stream>>>(x, xb, 4096 * 1024 / 4);
  k_tr<<<(3072 * 1024 / 8) / 256, 256, 0, stream>>>(Wattn, wat, 1024, 3072);
  k_tr<<<(1024 * 1024 / 8) / 256, 256, 0, stream>>>(Wproj, wpt, 1024, 1024);
  k_tab<<<(2048 * 32) / 256, 256, 0, stream>>>(cs);
  k_gemm_qkv<<<dim3(24, 32), 256, 0, stream>>>(xb, wat, battn, cs, qa, ka, va);
  k_trv<<<dim3(32, 32), 256, 0, stream>>>(va, vt);
  k_attn<<<512, 256, 0, stream>>>(qa, ka, vt, ob);
  k_gemm_proj<<<dim3(8, 32), 256, 0, stream>>>(ob, wpt, bproj, out);
}

// Round 4
// 142.661 us; speedup vs baseline: 1.4043x; 1.0787x over previous
//
#include <hip/hip_runtime.h>
#include <cstdint>
#include <cstddef>

// Problem constants: B=2, T=2048, C=1024, H=16, D=64
#define SEQ_T 2048
#define NHEAD 16

typedef __attribute__((ext_vector_type(8))) short short8;
typedef __attribute__((ext_vector_type(4))) float f32x4;

__device__ __forceinline__ unsigned short f2bf(float f) {
  union { float f; unsigned int u; } v; v.f = f;
  return (unsigned short)((v.u + 0x7FFFu + ((v.u >> 16) & 1u)) >> 16);
}

__device__ __forceinline__ unsigned cvtpk(float lo, float hi) {
  unsigned r;
  asm("v_cvt_pk_bf16_f32 %0, %1, %2" : "=v"(r) : "v"(lo), "v"(hi));
  return r;
}

__device__ __forceinline__ void gl_lds16(const void* g, void* l) {
  __builtin_amdgcn_global_load_lds(
      (__attribute__((address_space(1))) void*)(void*)g,
      (__attribute__((address_space(3))) void*)l, 16, 0, 0);
}

// ---------- fp32 -> bf16 convert (vectorized) ----------
__global__ void k_cvt(const float* __restrict__ in, unsigned short* __restrict__ out, int n4) {
  int i = blockIdx.x * 256 + threadIdx.x;
  if (i >= n4) return;
  float4 v = ((const float4*)in)[i];
  unsigned long long pk = (unsigned long long)f2bf(v.x)
                        | ((unsigned long long)f2bf(v.y) << 16)
                        | ((unsigned long long)f2bf(v.z) << 32)
                        | ((unsigned long long)f2bf(v.w) << 48);
  ((unsigned long long*)out)[i] = pk;
}

// ---------- [K,N] fp32 -> [N,K] bf16 transpose-convert ----------
__global__ void k_tr(const float* __restrict__ in, unsigned short* __restrict__ out, int K, int N) {
  int idx = blockIdx.x * 256 + threadIdx.x;
  int n = idx % N;
  int k0 = (idx / N) * 8;
  short8 v;
#pragma unroll
  for (int j = 0; j < 8; ++j)
    v[j] = (short)f2bf(in[(size_t)(k0 + j) * N + n]);
  *(short8*)&out[(size_t)n * K + k0] = v;
}

// ---------- RoPE cos/sin table [T][32] ----------
__global__ void k_tab(float2* __restrict__ tab) {
  int idx = blockIdx.x * 256 + threadIdx.x;
  int t = idx >> 5, i = idx & 31;
  float inv = powf(10000.0f, -(float)(2 * i) / 64.0f);
  float f = (float)t * inv;
  tab[idx] = make_float2(cosf(f), sinf(f));
}

// ---------- V transpose: [BH][T][D] -> [BH][D][T], swizzled LDS tile ----------
__global__ void k_trv(const unsigned short* __restrict__ v, unsigned short* __restrict__ vt) {
  __shared__ unsigned short tile[64 * 64];
  const int bh = blockIdx.y;
  const int t0 = blockIdx.x * 64;
  const int tid = threadIdx.x;
  const int r = tid >> 3, c8 = tid & 7;
  const size_t ib = (size_t)bh * SEQ_T * 64;
  {
    int ch0 = c8 ^ (r & 7) ^ ((r >> 3) & 7);
    *(short8*)&tile[r * 64 + ch0 * 8] =
        *(const short8*)&v[ib + (size_t)(t0 + r) * 64 + c8 * 8];
    int r2 = r + 32;
    int ch1 = c8 ^ (r2 & 7) ^ ((r2 >> 3) & 7);
    *(short8*)&tile[r2 * 64 + ch1 * 8] =
        *(const short8*)&v[ib + (size_t)(t0 + r2) * 64 + c8 * 8];
  }
  __syncthreads();
  const int d = tid >> 3, t8 = tid & 7;
  const size_t ob = (size_t)bh * 64 * SEQ_T;
#pragma unroll
  for (int p = 0; p < 2; ++p) {
    int dd = d + p * 32;
    short8 o;
#pragma unroll
    for (int j = 0; j < 8; ++j) {
      int t = t8 * 8 + j;
      int ch = (dd >> 3) ^ (t & 7) ^ ((t >> 3) & 7);
      o[j] = (short)tile[t * 64 + ch * 8 + (dd & 7)];
    }
    *(short8*)&vt[ob + (size_t)dd * SEQ_T + t0 + t8 * 8] = o;
  }
}

// ---------- GEMM1: qkv = x @ W_attn^T(+b), fused RoPE, scatter to q/k/v [B,H,T,D] ----------
__global__ void k_gemm_qkv(const unsigned short* __restrict__ A,
                           const unsigned short* __restrict__ Bt,
                           const float* __restrict__ bias,
                           const float2* __restrict__ cs,
                           unsigned short* __restrict__ qo,
                           unsigned short* __restrict__ ko,
                           unsigned short* __restrict__ vo) {
  __shared__ unsigned short lA[128 * 32];
  __shared__ unsigned short lB[128 * 32];
  const int K = 1024;
  const int bn = blockIdx.x, bm = blockIdx.y;
  const int tid = threadIdx.x, w = tid >> 6, l = tid & 63;
  const int lr = l & 15, lh = l >> 4;
  const int wm = w >> 1, wn = w & 1;

  f32x4 acc[4][4];
#pragma unroll
  for (int m = 0; m < 4; ++m)
#pragma unroll
    for (int n = 0; n < 4; ++n)
#pragma unroll
      for (int i = 0; i < 4; ++i) acc[m][n][i] = 0.f;

  const unsigned short* ga0 = A + (size_t)(bm * 128 + w * 16 + (l >> 2)) * K + (l & 3) * 8;
  const unsigned short* gb0 = Bt + (size_t)(bn * 128 + w * 16 + (l >> 2)) * K + (l & 3) * 8;
  unsigned short* la0 = &lA[w * 512];
  unsigned short* la1 = &lA[(w + 4) * 512];
  unsigned short* lb0 = &lB[w * 512];
  unsigned short* lb1 = &lB[(w + 4) * 512];

  for (int kt = 0; kt < K; kt += 32) {
    gl_lds16(ga0 + kt, la0);
    gl_lds16(ga0 + (size_t)64 * K + kt, la1);
    gl_lds16(gb0 + kt, lb0);
    gl_lds16(gb0 + (size_t)64 * K + kt, lb1);
    __syncthreads();
    short8 af[4], bf[4];
#pragma unroll
    for (int m = 0; m < 4; ++m) af[m] = *(const short8*)&lA[(wm * 64 + m * 16 + lr) * 32 + lh * 8];
#pragma unroll
    for (int n = 0; n < 4; ++n) bf[n] = *(const short8*)&lB[(wn * 64 + n * 16 + lr) * 32 + lh * 8];
#pragma unroll
    for (int m = 0; m < 4; ++m)
#pragma unroll
      for (int n = 0; n < 4; ++n)
        acc[m][n] = __builtin_amdgcn_mfma_f32_16x16x32_bf16(af[m], bf[n], acc[m][n], 0, 0, 0);
    __syncthreads();
  }

  const int col0 = bn * 128 + wn * 64;
  const int row0 = bm * 128 + wm * 64;
  const int sec = col0 >> 10;
  const int hh = (col0 >> 6) & 15;
  float bl[4];
#pragma unroll
  for (int n = 0; n < 4; ++n) bl[n] = bias[col0 + n * 16 + lr];

  if (sec == 2) {
#pragma unroll
    for (int m = 0; m < 4; ++m)
#pragma unroll
      for (int i = 0; i < 4; ++i) {
        int row = row0 + m * 16 + lh * 4 + i;
        int t = row & 2047, b = row >> 11;
        size_t ob = ((size_t)(b * 16 + hh) * 2048 + t) * 64;
#pragma unroll
        for (int n = 0; n < 4; ++n)
          vo[ob + n * 16 + lr] = f2bf(acc[m][n][i] + bl[n]);
      }
  } else {
    unsigned short* dst = (sec == 0) ? qo : ko;
#pragma unroll
    for (int m = 0; m < 4; ++m)
#pragma unroll
      for (int i = 0; i < 4; ++i) {
        int row = row0 + m * 16 + lh * 4 + i;
        int t = row & 2047, b = row >> 11;
        size_t ob = ((size_t)(b * 16 + hh) * 2048 + t) * 64;
#pragma unroll
        for (int n = 0; n < 4; ++n) {
          float v = acc[m][n][i] + bl[n];
          float pv = acc[m][n ^ 2][i] + bl[n ^ 2];
          int d = n * 16 + lr;
          float2 c = cs[t * 32 + (d & 31)];
          float rot = (d < 32) ? -pv : pv;
          dst[ob + d] = f2bf(v * c.x + rot * c.y);
        }
      }
  }
}

// ---------- flash attention: grid 1024 (XCD-chunked, CU-balanced qt), 256 thr ----------
// Swapped QK^T (S^T = mfma(K,Q)): lane owns one q-row (q=lr); P stays in registers
// via cvt_pk_bf16 + xor16/xor32 shuffle redistribution into PV A-fragments.
__global__ __launch_bounds__(256, 4) void k_attn(const unsigned short* __restrict__ Q,
                       const unsigned short* __restrict__ Kg,
                       const unsigned short* __restrict__ VT,
                       unsigned short* __restrict__ O) {
  __shared__ unsigned short kl[128 * 64];    // [kv][d] chunk-swizzled
  __shared__ unsigned short vl[64 * 128];    // [d][kv] chunk-swizzled
  const int id = blockIdx.x;
  const int xcd = id & 7, rr_ = id >> 3;
  const int g = rr_ >> 5, c_ = rr_ & 31;
  const int bh = xcd * 4 + g;                // 4 heads per XCD
  const int cc = (g & 2) ? ((c_ + 16) & 31) : c_;
  const int qt = (g & 1) ? (31 - cc) : cc;   // per-CU balanced: 4 co-resident blocks sum to 34 iters
  const int tid = threadIdx.x, w = tid >> 6, l = tid & 63;
  const int lr = l & 15, lh = l >> 4;
  const size_t base = (size_t)bh * SEQ_T * 64;
  const float CE = 0.18033688f;   // 0.125 * log2(e)
  const float DTHR = 44.3614f;    // 8 / CE

  const int qrow = qt * 64 + w * 16 + lr;    // this lane's q-row (softmax layout)
  const short8 qf0 = *(const short8*)&Q[base + (size_t)qrow * 64 + lh * 8];
  const short8 qf1 = *(const short8*)&Q[base + (size_t)qrow * 64 + lh * 8 + 32];

  // staging bases (swizzle terms are rep-invariant)
  const int ck = (tid & 7) ^ ((tid >> 3) & 7);
  const int cv = (tid & 15) ^ ((tid >> 4) & 7);
  const unsigned short* ks0 = Kg + base + (size_t)(tid >> 3) * 64 + ck * 8;
  const unsigned short* vs0 = VT + base + (size_t)(tid >> 4) * 2048 + cv * 8;
  unsigned short* kd = &kl[w * 64 * 8];
  unsigned short* vd = &vl[w * 64 * 8];

  float mi = -3.0e38f, li = 0.f;
  f32x4 ao[4];
#pragma unroll
  for (int n = 0; n < 4; ++n)
#pragma unroll
    for (int i = 0; i < 4; ++i) ao[n][i] = 0.f;

  const bool lo = (lh < 2);
  const bool mid = (lh == 1) || (lh == 2);
  const int lxor = lr & 7;

  const int nkt = (qt >> 1) + 1;
  for (int kt = 0; kt < nkt; ++kt) {
    __syncthreads();
    {
      const unsigned short* kp = ks0 + kt * 8192;
      const unsigned short* vp = vs0 + kt * 128;
      gl_lds16(kp,         kd);
      gl_lds16(kp + 2048,  kd + 2048);
      gl_lds16(kp + 4096,  kd + 4096);
      gl_lds16(kp + 6144,  kd + 6144);
      gl_lds16(vp,          vd);
      gl_lds16(vp + 32768,  vd + 2048);
      gl_lds16(vp + 65536,  vd + 4096);
      gl_lds16(vp + 98304,  vd + 6144);
    }
    __syncthreads();

    // S^T = K Q^T : lane holds q=qrow, kv = n*16 + lh*4 + i
    f32x4 s[8];
    __builtin_amdgcn_s_setprio(1);
#pragma unroll
    for (int n = 0; n < 8; ++n) {
      const int r = n * 16 + lr;
      const short8 kf0 = *(const short8*)&kl[r * 64 + ((lh ^ lxor) * 8)];
      const short8 kf1 = *(const short8*)&kl[r * 64 + (((lh + 4) ^ lxor) * 8)];
      f32x4 a;
#pragma unroll
      for (int i = 0; i < 4; ++i) a[i] = 0.f;
      a = __builtin_amdgcn_mfma_f32_16x16x32_bf16(kf0, qf0, a, 0, 0, 0);
      a = __builtin_amdgcn_mfma_f32_16x16x32_bf16(kf1, qf1, a, 0, 0, 0);
      s[n] = a;
    }
    __builtin_amdgcn_s_setprio(0);

    if (kt == nkt - 1) {   // diagonal tile: causal mask (unscaled scores)
#pragma unroll
      for (int n = 0; n < 8; ++n)
#pragma unroll
        for (int i = 0; i < 4; ++i) {
          int kvg = kt * 128 + n * 16 + lh * 4 + i;
          if (kvg > qrow) s[n][i] = -3.0e38f;
        }
    }

    // row max: per-lane over 32 vals, then combine across lh groups
    float tm;
    {
      float a0 = fmaxf(fmaxf(s[0][0], s[0][1]), fmaxf(s[0][2], s[0][3]));
#pragma unroll
      for (int n = 1; n < 8; ++n) {
        float b0 = fmaxf(fmaxf(s[n][0], s[n][1]), fmaxf(s[n][2], s[n][3]));
        a0 = fmaxf(a0, b0);
      }
      a0 = fmaxf(a0, __shfl_xor(a0, 16, 64));
      tm = fmaxf(a0, __shfl_xor(a0, 32, 64));
    }

    // T13 defer-rescale
    if (!__all(tm <= mi + DTHR)) {
      float mn = fmaxf(mi, tm);
      float scq = exp2f((mi - mn) * CE);
      mi = mn;
      li *= scq;
#pragma unroll
      for (int i = 0; i < 4; ++i) {
        float sci = __shfl(scq, lh * 4 + i, 64);   // rescale for PV row q=lh*4+i
#pragma unroll
        for (int n = 0; n < 4; ++n) ao[n][i] *= sci;
      }
    }

    const float miCE = mi * CE;
    float rs = 0.f;
#pragma unroll
    for (int n = 0; n < 8; ++n)
#pragma unroll
      for (int i = 0; i < 4; ++i) {
        float p = exp2f(fmaf(s[n][i], CE, -miCE));
        s[n][i] = p;
        rs += p;
      }
    rs += __shfl_xor(rs, 16, 64);
    rs += __shfl_xor(rs, 32, 64);
    li += rs;

    // pack P into PV A-fragments fully in-register (per ks = 32-kv block)
    short8 pa[4];
#pragma unroll
    for (int ks = 0; ks < 4; ++ks) {
      unsigned E0 = cvtpk(s[2 * ks][0], s[2 * ks][1]);
      unsigned E1 = cvtpk(s[2 * ks][2], s[2 * ks][3]);
      unsigned O0 = cvtpk(s[2 * ks + 1][0], s[2 * ks + 1][1]);
      unsigned O1 = cvtpk(s[2 * ks + 1][2], s[2 * ks + 1][3]);
      unsigned E0x = __shfl_xor(E0, 16, 64), E1x = __shfl_xor(E1, 16, 64);
      unsigned O0x = __shfl_xor(O0, 16, 64), O1x = __shfl_xor(O1, 16, 64);
      unsigned S0 = lo ? O0 : E0x, S1 = lo ? O1 : E1x;
      unsigned S2 = lo ? O0x : E0, S3 = lo ? O1x : E1;
      unsigned R0 = __shfl_xor(S0, 32, 64), R1 = __shfl_xor(S1, 32, 64);
      unsigned R2 = __shfl_xor(S2, 32, 64), R3 = __shfl_xor(S3, 32, 64);
      unsigned T0 = lo ? E0 : O0x, T1 = lo ? E1 : O1x;
      unsigned T2 = lo ? E0x : O0, T3 = lo ? E1x : O1;
      uint4 F;
      F.x = mid ? R0 : T0;
      F.y = mid ? R1 : T1;
      F.z = mid ? R2 : T2;
      F.w = mid ? R3 : T3;
      pa[ks] = __builtin_bit_cast(short8, F);
    }

    // O += P V : lane output rows q = lh*4+i, cols d = n*16+lr
    __builtin_amdgcn_s_setprio(1);
#pragma unroll
    for (int n = 0; n < 4; ++n) {
      const int r = n * 16 + lr;
#pragma unroll
      for (int ks = 0; ks < 4; ++ks) {
        const short8 vb = *(const short8*)&vl[r * 128 + (((ks * 4 + lh) ^ lxor) * 8)];
        ao[n] = __builtin_amdgcn_mfma_f32_16x16x32_bf16(pa[ks], vb, ao[n], 0, 0, 0);
      }
    }
    __builtin_amdgcn_s_setprio(0);
  }

  // write O in [B,T,C] bf16 (divide by row-sum fetched from softmax-layout lanes)
  const int hh = bh & 15, bb = bh >> 4;
  float rli[4];
#pragma unroll
  for (int i = 0; i < 4; ++i) rli[i] = 1.0f / __shfl(li, lh * 4 + i, 64);
#pragma unroll
  for (int n = 0; n < 4; ++n)
#pragma unroll
    for (int i = 0; i < 4; ++i) {
      int row = qt * 64 + w * 16 + lh * 4 + i;
      O[((size_t)(bb * 2048 + row)) * 1024 + hh * 64 + n * 16 + lr] = f2bf(ao[n][i] * rli[i]);
    }
}

// ---------- GEMM2: out = attn_out @ W_proj^T + b (fp32 out) ----------
__global__ void k_gemm_proj(const unsigned short* __restrict__ A,
                            const unsigned short* __restrict__ Bt,
                            const float* __restrict__ bias,
                            float* __restrict__ out) {
  __shared__ unsigned short lA[128 * 32];
  __shared__ unsigned short lB[128 * 32];
  const int K = 1024;
  const int bn = blockIdx.x, bm = blockIdx.y;
  const int tid = threadIdx.x, w = tid >> 6, l = tid & 63;
  const int lr = l & 15, lh = l >> 4;
  const int wm = w >> 1, wn = w & 1;

  f32x4 acc[4][4];
#pragma unroll
  for (int m = 0; m < 4; ++m)
#pragma unroll
    for (int n = 0; n < 4; ++n)
#pragma unroll
      for (int i = 0; i < 4; ++i) acc[m][n][i] = 0.f;

  const unsigned short* ga0 = A + (size_t)(bm * 128 + w * 16 + (l >> 2)) * K + (l & 3) * 8;
  const unsigned short* gb0 = Bt + (size_t)(bn * 128 + w * 16 + (l >> 2)) * K + (l & 3) * 8;
  unsigned short* la0 = &lA[w * 512];
  unsigned short* la1 = &lA[(w + 4) * 512];
  unsigned short* lb0 = &lB[w * 512];
  unsigned short* lb1 = &lB[(w + 4) * 512];

  for (int kt = 0; kt < K; kt += 32) {
    gl_lds16(ga0 + kt, la0);
    gl_lds16(ga0 + (size_t)64 * K + kt, la1);
    gl_lds16(gb0 + kt, lb0);
    gl_lds16(gb0 + (size_t)64 * K + kt, lb1);
    __syncthreads();
    short8 af[4], bf[4];
#pragma unroll
    for (int m = 0; m < 4; ++m) af[m] = *(const short8*)&lA[(wm * 64 + m * 16 + lr) * 32 + lh * 8];
#pragma unroll
    for (int n = 0; n < 4; ++n) bf[n] = *(const short8*)&lB[(wn * 64 + n * 16 + lr) * 32 + lh * 8];
#pragma unroll
    for (int m = 0; m < 4; ++m)
#pragma unroll
      for (int n = 0; n < 4; ++n)
        acc[m][n] = __builtin_amdgcn_mfma_f32_16x16x32_bf16(af[m], bf[n], acc[m][n], 0, 0, 0);
    __syncthreads();
  }

  const int col0 = bn * 128 + wn * 64;
  const int row0 = bm * 128 + wm * 64;
  float bl[4];
#pragma unroll
  for (int n = 0; n < 4; ++n) bl[n] = bias[col0 + n * 16 + lr];
#pragma unroll
  for (int m = 0; m < 4; ++m)
#pragma unroll
    for (int i = 0; i < 4; ++i) {
      int row = row0 + m * 16 + lh * 4 + i;
#pragma unroll
      for (int n = 0; n < 4; ++n)
        out[(size_t)row * 1024 + col0 + n * 16 + lr] = acc[m][n][i] + bl[n];
    }
}

extern "C" void kernel_launch(void* const* d_in, const int* in_sizes, int n_in,
                              void* d_out, int out_size, void* d_ws, size_t ws_size,
                              hipStream_t stream) {
  const float* x     = (const float*)d_in[0];
  const float* Wattn = (const float*)d_in[1];
  const float* battn = (const float*)d_in[2];
  const float* Wproj = (const float*)d_in[3];
  const float* bproj = (const float*)d_in[4];
  float* out = (float*)d_out;

  char* ws = (char*)d_ws;
  unsigned short* xb  = (unsigned short*)(ws);                  // 8 MB  x bf16 (reused as vt)
  unsigned short* wat = (unsigned short*)(ws + (8ull  << 20));  // 6 MB
  unsigned short* wpt = (unsigned short*)(ws + (14ull << 20));  // 2 MB
  unsigned short* qa  = (unsigned short*)(ws + (16ull << 20));  // 8 MB
  unsigned short* ka  = (unsigned short*)(ws + (24ull << 20));  // 8 MB
  unsigned short* va  = (unsigned short*)(ws + (32ull << 20));  // 8 MB
  unsigned short* ob  = (unsigned short*)(ws + (40ull << 20));  // 8 MB
  float2* cs          = (float2*)(ws + (48ull << 20));          // 512 KB
  unsigned short* vt  = xb;   // x bf16 dead after GEMM1; reuse for V^T

  k_cvt<<<(4096 * 1024 / 4) / 256, 256, 0, stream>>>(x, xb, 4096 * 1024 / 4);
  k_tr<<<(3072 * 1024 / 8) / 256, 256, 0, stream>>>(Wattn, wat, 1024, 3072);
  k_tr<<<(1024 * 1024 / 8) / 256, 256, 0, stream>>>(Wproj, wpt, 1024, 1024);
  k_tab<<<(2048 * 32) / 256, 256, 0, stream>>>(cs);
  k_gemm_qkv<<<dim3(24, 32), 256, 0, stream>>>(xb, wat, battn, cs, qa, ka, va);
  k_trv<<<dim3(32, 32), 256, 0, stream>>>(va, vt);
  k_attn<<<1024, 256, 0, stream>>>(qa, ka, vt, ob);
  k_gemm_proj<<<dim3(8, 32), 256, 0, stream>>>(ob, wpt, bproj, out);
}